// Round 6
// baseline (62.189 us; speedup 1.0000x reference)
//
#include <hip/hip_runtime.h>
#include <cstdio>

#define BB 2
#define TT 8
#define NNODE 5000
#define KK1 17
#define HH 4
#define NT (BB*TT*NNODE)          // 80000 (b,t,n) nodes
#define NREST (BB*7*NNODE)        // 70000 (b,t<7,n) rows for d_w
#define DEG_BLOCKS 10000
#define DW_BLOCKS 1094

typedef unsigned short u16;
typedef unsigned int u32;

__device__ __forceinline__ u16 f2bf(float x) {
  u32 u = __float_as_uint(x);
  u32 r = (u + 0x7fffu + ((u >> 16) & 1u)) >> 16;  // RNE
  return (u16)r;
}
__device__ __forceinline__ float bfLo(u32 w){ return __uint_as_float(w << 16); }
__device__ __forceinline__ float bfHi(u32 w){ return __uint_as_float(w & 0xffff0000u); }

// e = |a - b|^2 from bf16 h-slices (16 elems each), self-consistent with bf16 rows
__device__ __forceinline__ float edge_e(uint4 A0, uint4 A1, uint4 B0, uint4 B1) {
  u32 aw[8] = {A0.x,A0.y,A0.z,A0.w,A1.x,A1.y,A1.z,A1.w};
  u32 bw[8] = {B0.x,B0.y,B0.z,B0.w,B1.x,B1.y,B1.z,B1.w};
  float dot = 0.f, si = 0.f, sj = 0.f;
#pragma unroll
  for (int r = 0; r < 8; ++r) {
    float al = bfLo(aw[r]), ah = bfHi(aw[r]);
    float bl = bfLo(bw[r]), bh = bfHi(bw[r]);
    dot = fmaf(al, bl, dot); dot = fmaf(ah, bh, dot);
    si  = fmaf(al, al, si);  si  = fmaf(ah, ah, si);
    sj  = fmaf(bl, bl, sj);  sj  = fmaf(bh, bh, sj);
  }
  return si + sj - 2.f*dot;
}

// ---------------------------------------------------------------------------
// k_prep: feat -> g~ (bf16 [m][64]), a8~ (bf16 [m][32]), b8~ (bf16 [m][32]).
// XCD x owns m in [x*10000, (x+1)*10000).
__global__ void __launch_bounds__(256) k_prep(
    const float* __restrict__ feat, const float* __restrict__ mm,
    const float* __restrict__ q1, const float* __restrict__ q2,
    u16* __restrict__ g, u16* __restrict__ a8, u16* __restrict__ b8) {
  const int lane = threadIdx.x & 63;
  const int h = lane >> 4, i = lane & 15;
  const int bid = blockIdx.x;
  const int x = bid & 7;                                   // XCD
  const int local = (bid >> 3) * 4 + (threadIdx.x >> 6);   // 0..999 per XCD
  const int mbase = x * 10000 + local * 10;
  float Mrow[16], Qrow[16];
  const float* qsrc = (i < 8) ? (q1 + (h*8 + i)*16) : (q2 + (h*8 + (i - 8))*16);
#pragma unroll
  for (int j = 0; j < 16; ++j) {
    Mrow[j] = mm[(h*16 + i)*16 + j];
    Qrow[j] = qsrc[j];
  }
#pragma unroll 2
  for (int l = 0; l < 10; ++l) {
    const int m = mbase + l;
    const float4* fp = reinterpret_cast<const float4*>(feat + (size_t)m*64 + h*16);
    float fv[16];
#pragma unroll
    for (int q = 0; q < 4; ++q) {
      float4 v = fp[q];
      fv[q*4+0] = v.x; fv[q*4+1] = v.y; fv[q*4+2] = v.z; fv[q*4+3] = v.w;
    }
    float accG = 0.f, accQ = 0.f;
#pragma unroll
    for (int j = 0; j < 16; ++j) {
      accG = fmaf(Mrow[j], fv[j], accG);
      accQ = fmaf(Qrow[j], fv[j], accQ);
    }
    g[(size_t)m*64 + lane] = f2bf(accG);
    if (i < 8) a8[(size_t)m*32 + h*8 + i] = f2bf(accQ);
    else       b8[(size_t)m*32 + h*8 + (i - 8)] = f2bf(accQ);
  }
}

// ---------------------------------------------------------------------------
// Fused k_deg + k_dw.
// deg part (blocks [0,10000)): wave = node n on slices (2x, 2x+1); shared nn/j.
//   Stages w~ INTERLEAVED into the u_w output region: elem e at byte
//   32*(e>>3) + 2*(e&7)  (u16 index: (e>>3)*16 + (e&7)).
// dw part (blocks [10000,11094)): d_w rows, nn dedup via quad-shuffle,
//   LDS transpose epilogue for coalesced stores.
__global__ void __launch_bounds__(256) k_degdw(
    const u16* __restrict__ g, const u16* __restrict__ a8, const u16* __restrict__ b8,
    const int* __restrict__ nn, float* __restrict__ deg,
    u16* __restrict__ wstage, float* __restrict__ dw) {
  __shared__ float lds[64*68];
  const int bid = blockIdx.x;
  if (bid < DEG_BLOCKS) {
    const int x = bid & 7;                              // XCD, owns slices 2x,2x+1
    const int n = (bid >> 3)*4 + (threadIdx.x >> 6);    // 0..4999
    const int lane = threadIdx.x & 63;
    const int k = lane >> 2, h = lane & 3;
    const int m0 = (2*x)*NNODE + n;
    const int m1 = m0 + NNODE;
    int jr = nn[n*KK1 + 1 + k];
    bool v = jr >= 0;
    int j = v ? jr : 0;
    const uint4* pi0 = reinterpret_cast<const uint4*>(g + (size_t)m0*64 + h*16);
    const uint4* pi1 = reinterpret_cast<const uint4*>(g + (size_t)m1*64 + h*16);
    const uint4* pj0 = reinterpret_cast<const uint4*>(g + (size_t)((2*x)*NNODE + j)*64 + h*16);
    const uint4* pj1 = reinterpret_cast<const uint4*>(g + (size_t)((2*x+1)*NNODE + j)*64 + h*16);
    uint4 A00 = pi0[0], A01 = pi0[1];
    uint4 A10 = pi1[0], A11 = pi1[1];
    uint4 B00 = pj0[0], B01 = pj0[1];
    uint4 B10 = pj1[0], B11 = pj1[1];
    float e0 = edge_e(A00, A01, B00, B01);
    float e1 = edge_e(A10, A11, B10, B11);
    float w0 = v ? __expf(-e0) : 0.f;
    float w1 = v ? __expf(-e1) : 0.f;
    // interleaved staging: u16 index = m*128 + (lane>>3)*16 + (lane&7)
    const int soff = ((lane >> 3) << 4) + (lane & 7);
    wstage[(size_t)m0*128 + soff] = f2bf(w0);
    wstage[(size_t)m1*128 + soff] = f2bf(w1);
    float d0 = w0, d1 = w1;
    d0 += __shfl_xor(d0, 4);  d1 += __shfl_xor(d1, 4);
    d0 += __shfl_xor(d0, 8);  d1 += __shfl_xor(d1, 8);
    d0 += __shfl_xor(d0, 16); d1 += __shfl_xor(d1, 16);
    d0 += __shfl_xor(d0, 32); d1 += __shfl_xor(d1, 32);
    if (lane < 4) {
      deg[m0*4 + lane] = d0;
      deg[m1*4 + lane] = d1;
    }
  } else {
    const int wg = bid - DEG_BLOCKS;            // 0..1093
    const int lr = threadIdx.x >> 2;            // 0..63
    const int h  = threadIdx.x & 3;
    const int lane = threadIdx.x & 63;
    const int qbase = lane & ~3;                // quad leader
    const int rest = wg*64 + lr;
    if (rest < NREST) {
      const int n = rest % NNODE;
      const int q2 = rest / NNODE;              // 0..13
      const int b = q2 / 7, t = q2 % 7;
      uint4 Bv = *reinterpret_cast<const uint4*>(b8 + ((size_t)((b*TT + t + 1)*NNODE + n))*32 + h*8);
      float bv[8] = {bfLo(Bv.x), bfHi(Bv.x), bfLo(Bv.y), bfHi(Bv.y),
                     bfLo(Bv.z), bfHi(Bv.z), bfLo(Bv.w), bfHi(Bv.w)};
      const int nbase = n*KK1;
      const int abase = (b*TT + t)*NNODE;
      // nn dedup: lane h holds entries {h, h+4, h+8, h+12}; entry 16 broadcast.
      int jvec[4];
      jvec[0] = nn[nbase + h + 0];
      jvec[1] = nn[nbase + h + 4];
      jvec[2] = nn[nbase + h + 8];
      jvec[3] = nn[nbase + h + 12];
      int j16 = nn[nbase + 16];
      float wk[17];
      float indeg = 0.f;
#pragma unroll
      for (int kk = 0; kk < 16; ++kk) {
        int jr = __shfl(jvec[kk >> 2], qbase + (kk & 3));
        bool valid = jr >= 0;
        int j = valid ? jr : 0;
        uint4 Av = *reinterpret_cast<const uint4*>(a8 + ((size_t)(abase + j))*32 + h*8);
        float dot = 0.f;
        dot = fmaf(bfLo(Av.x), bv[0], dot); dot = fmaf(bfHi(Av.x), bv[1], dot);
        dot = fmaf(bfLo(Av.y), bv[2], dot); dot = fmaf(bfHi(Av.y), bv[3], dot);
        dot = fmaf(bfLo(Av.z), bv[4], dot); dot = fmaf(bfHi(Av.z), bv[5], dot);
        dot = fmaf(bfLo(Av.w), bv[6], dot); dot = fmaf(bfHi(Av.w), bv[7], dot);
        float w = valid ? __expf(-dot) : 0.f;
        wk[kk] = w;
        indeg += w;
      }
      {
        bool valid = j16 >= 0;
        int j = valid ? j16 : 0;
        uint4 Av = *reinterpret_cast<const uint4*>(a8 + ((size_t)(abase + j))*32 + h*8);
        float dot = 0.f;
        dot = fmaf(bfLo(Av.x), bv[0], dot); dot = fmaf(bfHi(Av.x), bv[1], dot);
        dot = fmaf(bfLo(Av.y), bv[2], dot); dot = fmaf(bfHi(Av.y), bv[3], dot);
        dot = fmaf(bfLo(Av.z), bv[4], dot); dot = fmaf(bfHi(Av.z), bv[5], dot);
        dot = fmaf(bfLo(Av.w), bv[6], dot); dot = fmaf(bfHi(Av.w), bv[7], dot);
        float w = valid ? __expf(-dot) : 0.f;
        wk[16] = w;
        indeg += w;
      }
      // note: wk[0] corresponds to original k=0 (self edge, nn[...,0] = n)
      float inv = (indeg > 0.f) ? (1.0f / indeg) : 0.f;
#pragma unroll
      for (int kk = 0; kk < KK1; ++kk) lds[lr*68 + kk*4 + h] = wk[kk] * inv;
    }
    __syncthreads();
    const int rows = NREST - wg*64;
    const int nchunks = (rows >= 64 ? 64 : rows) * 17;    // float4 chunks
    float4* obase = reinterpret_cast<float4*>(dw + (size_t)wg*4352);
    for (int c = threadIdx.x; c < nchunks; c += 256) {
      const int row = c / 17;
      const int col = (c % 17) * 4;
      obase[c] = *reinterpret_cast<const float4*>(&lds[row*68 + col]);
    }
  }
}

// ---------------------------------------------------------------------------
// k_uw: normalize in place. Thread owns output bytes [4*idx8, 4*idx8+32);
// staged w~ occupies the first 16 of those bytes (read-before-write, same thread).
// Grid 2500 (bijective 8-way, q=312 r=4).
__global__ void __launch_bounds__(256) k_uw(
    const int* __restrict__ nn, const float* __restrict__ deg,
    float* __restrict__ uw) {
  const int bid = blockIdx.x;
  const int x = bid & 7, sub = bid >> 3;
  const int wg = (x < 4 ? x*313 : 4*313 + (x-4)*312) + sub;
  const int idx8 = (wg * 256 + threadIdx.x) * 8;
  const int m = idx8 >> 6;
  const int r8 = idx8 & 63;
  const int k0 = r8 >> 2;
  const int n = m % NNODE;
  const int btb = m - n;
  uint4 wv = *reinterpret_cast<const uint4*>(uw + idx8);   // staged bf16 x8
  int jr0 = nn[n*KK1 + 1 + k0];
  int jr1 = nn[n*KK1 + 2 + k0];
  float4 di = *reinterpret_cast<const float4*>(deg + (size_t)m*4);
  uint4 o0 = {0u,0u,0u,0u}, o1 = {0u,0u,0u,0u};
  if (jr0 >= 0) {
    float4 dj = *reinterpret_cast<const float4*>(deg + (size_t)(btb + jr0)*4);
    float w0 = bfLo(wv.x), w1 = bfHi(wv.x), w2 = bfLo(wv.y), w3 = bfHi(wv.y);
    float p0 = di.x*dj.x, p1 = di.y*dj.y, p2 = di.z*dj.z, p3 = di.w*dj.w;
    o0.x = __float_as_uint((w0 > 0.f && p0 > 0.f) ? w0 * rsqrtf(p0) : 0.f);
    o0.y = __float_as_uint((w1 > 0.f && p1 > 0.f) ? w1 * rsqrtf(p1) : 0.f);
    o0.z = __float_as_uint((w2 > 0.f && p2 > 0.f) ? w2 * rsqrtf(p2) : 0.f);
    o0.w = __float_as_uint((w3 > 0.f && p3 > 0.f) ? w3 * rsqrtf(p3) : 0.f);
  }
  if (jr1 >= 0) {
    float4 dj = *reinterpret_cast<const float4*>(deg + (size_t)(btb + jr1)*4);
    float w0 = bfLo(wv.z), w1 = bfHi(wv.z), w2 = bfLo(wv.w), w3 = bfHi(wv.w);
    float p0 = di.x*dj.x, p1 = di.y*dj.y, p2 = di.z*dj.z, p3 = di.w*dj.w;
    o1.x = __float_as_uint((w0 > 0.f && p0 > 0.f) ? w0 * rsqrtf(p0) : 0.f);
    o1.y = __float_as_uint((w1 > 0.f && p1 > 0.f) ? w1 * rsqrtf(p1) : 0.f);
    o1.z = __float_as_uint((w2 > 0.f && p2 > 0.f) ? w2 * rsqrtf(p2) : 0.f);
    o1.w = __float_as_uint((w3 > 0.f && p3 > 0.f) ? w3 * rsqrtf(p3) : 0.f);
  }
  uint4* ob = reinterpret_cast<uint4*>(uw + idx8);
  ob[0] = o0;
  ob[1] = o1;
}

extern "C" void kernel_launch(void* const* d_in, const int* in_sizes, int n_in,
                              void* d_out, int out_size, void* d_ws, size_t ws_size,
                              hipStream_t stream) {
  const float* feat = (const float*)d_in[0];
  const int*   nn   = (const int*)d_in[1];
  const float* q1   = (const float*)d_in[2];
  const float* q2   = (const float*)d_in[3];
  const float* mm   = (const float*)d_in[4];
  float* uw = (float*)d_out;
  float* dw = uw + (size_t)NT*64;                 // 5,120,000 elems in

  const size_t G_BYTES  = (size_t)NT*64*2;        // 10,240,000
  const size_t A_BYTES  = (size_t)NT*32*2;        //  5,120,000
  const size_t DEG_BYTES= (size_t)NT*4*4;         //  1,280,000
  const size_t NEED = G_BYTES + 2*A_BYTES + DEG_BYTES;  // 21,760,000
  if (ws_size < NEED) {
    fprintf(stderr, "kernel_launch: ws_size %zu < needed %zu\n", ws_size, NEED);
    return;
  }
  u16*   g   = (u16*)d_ws;
  u16*   a8  = (u16*)((char*)d_ws + G_BYTES);
  u16*   b8  = (u16*)((char*)d_ws + G_BYTES + A_BYTES);
  float* deg = (float*)((char*)d_ws + G_BYTES + 2*A_BYTES);
  u16*   wstage = (u16*)uw;    // interleaved staging inside u_w region

  k_prep <<<2000, 256, 0, stream>>>(feat, mm, q1, q2, g, a8, b8);
  k_degdw<<<DEG_BLOCKS + DW_BLOCKS, 256, 0, stream>>>(g, a8, b8, nn, deg, wstage, dw);
  k_uw   <<<2500, 256, 0, stream>>>(nn, deg, uw);
}